// Round 1
// baseline (232.201 us; speedup 1.0000x reference)
//
#include <hip/hip_runtime.h>

// Attention fwd, B=16 S=4096 D=64, fp32 in/out, bf16 MFMA flash kernel.
// Per block: 128 q rows (4 waves x 32). Key tiles of 32, double-buffered LDS.
// S^T = K*Q^T via mfma_f32_32x32x16_bf16 so per-lane scores share one q row.

#define S_LEN 4096
#define HD    64
#define KT    32
#define QW    32
#define NT    (S_LEN / KT)   // 128 key tiles
#define KSTR  72             // Kld row stride (elems): 144B, 16B-aligned, conflict-free
#define VSTR  40             // Vtld row stride: 80B, 16B-aligned
#define PSTR  40             // Pld row stride: 80B

typedef __bf16 bf16x8 __attribute__((ext_vector_type(8)));
typedef float  f32x16 __attribute__((ext_vector_type(16)));

// round-half-up fp32->bf16 (unbiased vs truncation), pack two into a dword
__device__ __forceinline__ unsigned int pack_bf16(float x, float y) {
  unsigned int ux = __builtin_bit_cast(unsigned int, x) + 0x8000u;
  unsigned int uy = __builtin_bit_cast(unsigned int, y) + 0x8000u;
  return (ux >> 16) | (uy & 0xffff0000u);
}
__device__ __forceinline__ __bf16 to_bf16(float x) {
  unsigned short us =
      (unsigned short)((__builtin_bit_cast(unsigned int, x) + 0x8000u) >> 16);
  return __builtin_bit_cast(__bf16, us);
}

__global__ __launch_bounds__(256, 3) void attn_fwd(
    const float* __restrict__ Qg, const float* __restrict__ Kg,
    const float* __restrict__ Vg, float* __restrict__ Og) {
  const int bid = blockIdx.x;
  // XCD-aware swizzle: blocks with same bid%8 (same XCD, assuming round-robin)
  // share 2 batches -> K+V fp32 working set ~4MB fits XCD L2.
  const int batch = ((bid & 7) << 1) | (bid >> 8);
  const int qt    = (bid >> 3) & 31;
  const int q0    = qt << 7;   // *128

  const int tid  = threadIdx.x;
  const int wave = tid >> 6;
  const int lane = tid & 63;
  const int l32  = lane & 31;
  const int h    = lane >> 5;  // 0/1

  const size_t boff = (size_t)batch * (S_LEN * HD);
  const float* __restrict__ Qb = Qg + boff;
  const float* __restrict__ Kb = Kg + boff;
  const float* __restrict__ Vb = Vg + boff;
  float* __restrict__ Ob = Og + boff;

  __shared__ __align__(16) __bf16 Kld[2][KT * KSTR];   // [key][d]   9216 B
  __shared__ __align__(16) __bf16 Vtld[2][HD * VSTR];  // [d][key]  10240 B
  __shared__ __align__(16) __bf16 Pld[4][QW * PSTR];   // per-wave P 10240 B

  // ---- persistent Q fragments (B-operand layout: n=l32 -> q, k=h*8+j -> d) ----
  const int qrow = q0 + wave * QW + l32;
  bf16x8 qf[4];
#pragma unroll
  for (int dc = 0; dc < 4; ++dc) {
    const float* p = Qb + qrow * HD + dc * 16 + h * 8;
    float4 a = *(const float4*)p;
    float4 b = *(const float4*)(p + 4);
    uint4 uu;
    uu.x = pack_bf16(a.x, a.y);
    uu.y = pack_bf16(a.z, a.w);
    uu.z = pack_bf16(b.x, b.y);
    uu.w = pack_bf16(b.z, b.w);
    qf[dc] = __builtin_bit_cast(bf16x8, uu);
  }

  // ---- stage key-tile 0 into buffer 0 ----
  {
#pragma unroll
    for (int k = 0; k < 4; ++k) {
      const int e = 2 * (tid + (k << 8));             // K: flat, coalesced
      float2 kv = *(const float2*)(Kb + e);
      *(unsigned int*)&Kld[0][(e >> 6) * KSTR + (e & 63)] = pack_bf16(kv.x, kv.y);
      const int idx = tid + (k << 8);                 // V: key-major -> 2-way LDS writes
      const int key = idx & 31, dp = idx >> 5;
      float2 vv = *(const float2*)(Vb + key * HD + 2 * dp);
      Vtld[0][(2 * dp) * VSTR + key]     = to_bf16(vv.x);
      Vtld[0][(2 * dp + 1) * VSTR + key] = to_bf16(vv.y);
    }
  }

  f32x16 acc0{};   // out cols d = 0..31   (C layout: col=l32, row formula -> q)
  f32x16 acc1{};   // out cols d = 32..63
  float rowsum = 0.0f;                       // partial for q=l32 over this h's keys
  const float cs = 0.18033688011112042f;     // (1/8) * log2(e)

  for (int kt = 0; kt < NT; ++kt) {
    __syncthreads();
    const int cb = kt & 1;
    const bool pre = (kt + 1 < NT);

    // prefetch next tile's fp32 into regs (consumed after compute)
    float2 kpre[4], vpre[4];
    if (pre) {
      const float* ksrc = Kb + (kt + 1) * (KT * HD);
      const float* vsrc = Vb + (kt + 1) * (KT * HD);
#pragma unroll
      for (int k = 0; k < 4; ++k) {
        const int e = 2 * (tid + (k << 8));
        kpre[k] = *(const float2*)(ksrc + e);
        const int idx = tid + (k << 8);
        const int key = idx & 31, dp = idx >> 5;
        vpre[k] = *(const float2*)(vsrc + key * HD + 2 * dp);
      }
    }

    // ---- S^T = K * Q^T : A=K (m=key), B=Q^T (n=q), chained over d chunks ----
    f32x16 s{};
#pragma unroll
    for (int dc = 0; dc < 4; ++dc) {
      bf16x8 ka = *(const bf16x8*)&Kld[cb][l32 * KSTR + dc * 16 + h * 8];
      s = __builtin_amdgcn_mfma_f32_32x32x16_bf16(ka, qf[dc], s, 0, 0, 0);
    }

    // ---- unnormalized softmax: p = exp2(s*cs); all 16 values share q=l32 ----
    // reg r -> key = (r&3) + 8*(r>>2) + 4*h : groups of 4 contiguous keys
#pragma unroll
    for (int g = 0; g < 4; ++g) {
      float p0 = __builtin_amdgcn_exp2f(s[4 * g + 0] * cs);
      float p1 = __builtin_amdgcn_exp2f(s[4 * g + 1] * cs);
      float p2 = __builtin_amdgcn_exp2f(s[4 * g + 2] * cs);
      float p3 = __builtin_amdgcn_exp2f(s[4 * g + 3] * cs);
      rowsum += (p0 + p1) + (p2 + p3);
      uint2 w;
      w.x = pack_bf16(p0, p1);
      w.y = pack_bf16(p2, p3);
      *(uint2*)&Pld[wave][l32 * PSTR + g * 8 + h * 4] = w;   // b64, 8B-aligned
    }
    // P is wave-private: wave-local LDS drain is enough (no barrier)
    asm volatile("s_waitcnt lgkmcnt(0)" ::: "memory");

    // ---- O += P * V : A=P (m=q), B=V via V^T rows (n=d), 2 key chunks ----
#pragma unroll
    for (int kc = 0; kc < 2; ++kc) {
      bf16x8 pa  = *(const bf16x8*)&Pld[wave][l32 * PSTR + kc * 16 + h * 8];
      bf16x8 vb0 = *(const bf16x8*)&Vtld[cb][l32 * VSTR + kc * 16 + h * 8];
      bf16x8 vb1 = *(const bf16x8*)&Vtld[cb][(32 + l32) * VSTR + kc * 16 + h * 8];
      acc0 = __builtin_amdgcn_mfma_f32_32x32x16_bf16(pa, vb0, acc0, 0, 0, 0);
      acc1 = __builtin_amdgcn_mfma_f32_32x32x16_bf16(pa, vb1, acc1, 0, 0, 0);
    }

    // ---- convert+write prefetched tile into the other buffer ----
    if (pre) {
      const int nb = cb ^ 1;
#pragma unroll
      for (int k = 0; k < 4; ++k) {
        const int e = 2 * (tid + (k << 8));
        *(unsigned int*)&Kld[nb][(e >> 6) * KSTR + (e & 63)] =
            pack_bf16(kpre[k].x, kpre[k].y);
        const int idx = tid + (k << 8);
        const int key = idx & 31, dp = idx >> 5;
        Vtld[nb][(2 * dp) * VSTR + key]     = to_bf16(vpre[k].x);
        Vtld[nb][(2 * dp + 1) * VSTR + key] = to_bf16(vpre[k].y);
      }
    }
  }

  // ---- epilogue: rowsum across h halves, divide, store ----
  float rs  = rowsum + __shfl_xor(rowsum, 32, 64);
  float inv = 1.0f / rs;
#pragma unroll
  for (int r = 0; r < 16; ++r) {
    const int qrl  = (r & 3) + ((r >> 2) << 3) + (h << 2);  // C-layout row -> q
    const float iv = __shfl(inv, qrl, 64);                  // rowsum lives at lane q
    float* op = Ob + (size_t)(q0 + wave * QW + qrl) * HD + l32;
    op[0]  = acc0[r] * iv;
    op[32] = acc1[r] * iv;
  }
}

extern "C" void kernel_launch(void* const* d_in, const int* in_sizes, int n_in,
                              void* d_out, int out_size, void* d_ws, size_t ws_size,
                              hipStream_t stream) {
  const float* Q = (const float*)d_in[0];
  const float* K = (const float*)d_in[1];
  const float* V = (const float*)d_in[2];
  float* O = (float*)d_out;
  attn_fwd<<<dim3(512), dim3(256), 0, stream>>>(Q, K, V, O);
}